// Round 16
// baseline (177.760 us; speedup 1.0000x reference)
//
#include <hip/hip_runtime.h>
#include <hip/hip_bf16.h>
#include <hip/hip_cooperative_groups.h>

namespace cg = cooperative_groups;

// Node_EncodingBlock on MI355X. Inputs fp32, output fp32.
// R16: cooperative mega-kernel, defensively engineered after R15's silent
// launch failure (all-zeros => coop launch rejected, no error check):
//  - 250 blocks (<= 256 CUs: co-resident even at 1 block/CU); each phase
//    handles tiles blk and blk+250.
//  - host CHECKS the coop return code and falls back to the validated R14
//    5-kernel chain on any failure (deterministic per environment).
//  - phase bodies are shared __device__ functions (one implementation for
//    both paths), byte-level ports of the R12/R14-validated code.

#define BN_EPS 1e-5f
// ws float offsets
#define WS_X1    256000     // [2000][128]
#define WS_X2    512000     // [2000][128]
#define WS_SUM1  768000     // [128]; SQ1 contiguous at +128
#define WS_SQ1   768128
#define WS_SUM2  768256
#define WS_SQ2   768384
#define WS_UV    768512
#define WS_C0V   768640
#define BN1P     770000     // [500][256]
#define BN2P     900000     // [500][256]

struct P {
  const float *cost, *rnd, *dem, *Wv, *mix1w, *mix1b, *mix2w, *mix2b, *Wo, *bo;
  const float *W1, *b1, *g1, *bb1, *W2, *b2, *Wn, *Wd, *bd, *bnn, *g2, *bb2;
  float *out, *ws;
};

// 2-row GEMM micro-step (attn phase D / final)
#define GB8_R2(WPTR, LDW, KIDX, ACT2D, ACC)                             \
  {                                                                     \
    float4 w[8];                                                        \
    _Pragma("unroll")                                                   \
    for (int u = 0; u < 8; ++u)                                         \
      w[u] = *(const float4*)((WPTR) + (size_t)((KIDX) + u) * (LDW));   \
    _Pragma("unroll")                                                   \
    for (int u = 0; u < 8; ++u) {                                       \
      _Pragma("unroll")                                                 \
      for (int r = 0; r < 2; ++r) {                                     \
        float a = ACT2D[r][u];                                          \
        ACC[r][0] = fmaf(a, w[u].x, ACC[r][0]);                         \
        ACC[r][1] = fmaf(a, w[u].y, ACC[r][1]);                         \
        ACC[r][2] = fmaf(a, w[u].z, ACC[r][2]);                         \
        ACC[r][3] = fmaf(a, w[u].w, ACC[r][3]);                         \
      }                                                                 \
    }                                                                   \
  }

#define LD_AV2(SRC_ROW0, SRC_ROW1, KIDX, ACT2D)                         \
  {                                                                     \
    float4 x0 = *(const float4*)&(SRC_ROW0)[(KIDX)];                    \
    float4 y0 = *(const float4*)&(SRC_ROW0)[(KIDX) + 4];                \
    float4 x1 = *(const float4*)&(SRC_ROW1)[(KIDX)];                    \
    float4 y1 = *(const float4*)&(SRC_ROW1)[(KIDX) + 4];                \
    ACT2D[0][0]=x0.x; ACT2D[0][1]=x0.y; ACT2D[0][2]=x0.z; ACT2D[0][3]=x0.w; \
    ACT2D[0][4]=y0.x; ACT2D[0][5]=y0.y; ACT2D[0][6]=y0.z; ACT2D[0][7]=y0.w; \
    ACT2D[1][0]=x1.x; ACT2D[1][1]=x1.y; ACT2D[1][2]=x1.z; ACT2D[1][3]=x1.w; \
    ACT2D[1][4]=y1.x; ACT2D[1][5]=y1.y; ACT2D[1][6]=y1.z; ACT2D[1][7]=y1.w; \
  }

// 4-row x 4-col x 4-k batch: 4 independent float4 weight loads, 64 FMAs.
#define GB4_R4(WPTR, LDW, K0, SRC2D, ACC)                               \
  {                                                                     \
    float4 w[4];                                                        \
    _Pragma("unroll")                                                   \
    for (int u = 0; u < 4; ++u)                                         \
      w[u] = *(const float4*)((WPTR) + (size_t)((K0) + u) * (LDW));     \
    float av[4][4];                                                     \
    _Pragma("unroll")                                                   \
    for (int r = 0; r < 4; ++r) {                                       \
      float4 x = *(const float4*)&SRC2D[r][(K0)];                       \
      av[r][0] = x.x; av[r][1] = x.y; av[r][2] = x.z; av[r][3] = x.w;   \
    }                                                                   \
    _Pragma("unroll")                                                   \
    for (int u = 0; u < 4; ++u) {                                       \
      _Pragma("unroll")                                                 \
      for (int r = 0; r < 4; ++r) {                                     \
        ACC[r][0] = fmaf(av[r][u], w[u].x, ACC[r][0]);                  \
        ACC[r][1] = fmaf(av[r][u], w[u].y, ACC[r][1]);                  \
        ACC[r][2] = fmaf(av[r][u], w[u].z, ACC[r][2]);                  \
        ACC[r][3] = fmaf(av[r][u], w[u].w, ACC[r][3]);                  \
      }                                                                 \
    }                                                                   \
  }

struct SmA {
  float scost[4][512];
  float2 lut[2048];
  float aw[32][132];
  float soc[4][132];
  float sP[8][512];          // also traw scratch (2056 <= 4096)
  float svr[128];
  float mu[8][16], mr[8][16], mA[8], mB[8];
  int   sperm[128];
  float sS[512], sQ[512];
};
struct SmF {
  float o1[4][128];
  float sY[4][512];
  float sP[4][4][512];       // GEMM2 view [16][4][128]
  float sS[512], sQ[512];
};
struct SmC {
  float o3[4][132];
  float sP[8][4][128];
};
struct SmR { float stage[512]; };
union Sm { SmA a; SmF f; SmC c; SmR r; };

// ---- attn phase: attention + multi_head_combine + BN1 partials ------------
__device__ __forceinline__ void attn_phase(const P& p, int blk, SmA& a) {
  const int t = threadIdx.x;
  const int lane = t & 63;
  const int row0 = blk * 4;
  const int b = blk / 125;
  float* ws = p.ws;
  {
    int rr = t >> 7, i4 = t & 127;
    *(float4*)&a.scost[rr][i4 * 4] = (i4 < 125)
        ? *(const float4*)(p.cost + (size_t)(row0 + rr) * 500 + i4 * 4)
        : float4{0.f, 0.f, 0.f, 0.f};
  }
  if (t < 128) a.svr[t] = p.rnd[b * 128 + t];
  __syncthreads();
  if (t < 128) {
    float vt = a.svr[t];
    int rank = 0;
    for (int j = 0; j < 128; ++j) {
      float vj = a.svr[j];
      rank += (vj < vt) || (vj == vt && j < t);
    }
    a.sperm[rank] = t;
    // abs-form MLP params: g(c) = A c + B + sum u_s |c - r_s|
    int h = t >> 4, s = t & 15;
    float w1  = p.mix1w[h * 32 + 16 + s];
    float b1v = p.mix1b[h * 16 + s];
    float w2  = p.mix2w[h * 16 + s];
    bool tiny = fabsf(w1) < 1e-20f;
    float us = tiny ? 0.f : 0.5f * w2 * fabsf(w1);
    float rs = tiny ? 0.f : -b1v / w1;
    float Ap = 0.5f * w2 * w1;
    float Bp = 0.5f * w2 * b1v + (tiny ? 0.5f * w2 * fabsf(b1v) : 0.f);
    a.mu[h][s] = us; a.mr[h][s] = rs;
#pragma unroll
    for (int off = 1; off < 16; off <<= 1) {
      Ap += __shfl_xor(Ap, off);
      Bp += __shfl_xor(Bp, off);
    }
    if (s == 0) { a.mA[h] = Ap; a.mB[h] = Bp + p.mix2b[h]; }
  }
  __syncthreads();
  float* traw = &a.sP[0][0];
  if (t < 257) {
    float x = (float)t * (1.f / 255.f);
    for (int h = 0; h < 8; ++h) {
      float g = fmaf(x, a.mA[h], a.mB[h]);
#pragma unroll
      for (int s = 0; s < 16; ++s)
        g = fmaf(fabsf(x - a.mr[h][s]), a.mu[h][s], g);
      traw[h * 257 + t] = __expf(g);
    }
  }
  __syncthreads();
#pragma unroll
  for (int pq = 0; pq < 4; ++pq) {
    int e = t + pq * 512;
    int h = e >> 8, i = e & 255;
    float av = traw[h * 257 + i];
    a.lut[e] = float2{av, traw[h * 257 + i + 1] - av};
  }
  __syncthreads();
  // phase B: wave (row, head-half): LUT scores -> aggregated softmax weights
  {
    const int wid = t >> 6;
    const int r  = wid & 3;
    const int h0 = (wid >> 2) * 4;
    float cv8[8];
#pragma unroll
    for (int ii = 0; ii < 8; ++ii) cv8[ii] = a.scost[r][ii * 64 + lane];
    for (int h = h0; h < h0 + 4; ++h) {
      const float2* lh = &a.lut[h * 256];
      float wsum = 0.f, a0 = 0.f, a1 = 0.f;
#pragma unroll
      for (int ii = 0; ii < 8; ++ii) {
        float u = cv8[ii] * 255.f;
        int i = (int)u;
        float f = u - (float)i;
        float2 td = lh[i];
        float e = fmaf(td.y, f, td.x);
        if (ii == 7 && lane >= 52) e = 0.f;   // mask m >= 500
        wsum += e;
        if (ii & 1) a1 += e; else a0 += e;
      }
#pragma unroll
      for (int off = 32; off; off >>= 1) wsum += __shfl_xor(wsum, off);
      float inv = 1.f / wsum;
      a.aw[r * 8 + h][lane]      = a0 * inv;
      a.aw[r * 8 + h][64 + lane] = a1 * inv;
    }
  }
  __syncthreads();
  // phase C: oc[r][c] = sum_j aw[r*8+(c>>4)][j] * Wv[perm[j]][c]; j-split 4
  {
    const int c  = t & 127;
    const int jh = t >> 7;
    const int h  = c >> 4;
    float acc4[4] = {0.f, 0.f, 0.f, 0.f};
    for (int jb = jh * 32; jb < jh * 32 + 32; jb += 8) {
      int rows[8];
#pragma unroll
      for (int u = 0; u < 8; ++u) rows[u] = a.sperm[jb + u];
      float wv8[8];
#pragma unroll
      for (int u = 0; u < 8; ++u) wv8[u] = p.Wv[(size_t)rows[u] * 128 + c];
#pragma unroll
      for (int r = 0; r < 4; ++r) {
        float4 aa = *(const float4*)&a.aw[r * 8 + h][jb];
        float4 ab = *(const float4*)&a.aw[r * 8 + h][jb + 4];
        acc4[r] = fmaf(aa.x, wv8[0], acc4[r]);
        acc4[r] = fmaf(aa.y, wv8[1], acc4[r]);
        acc4[r] = fmaf(aa.z, wv8[2], acc4[r]);
        acc4[r] = fmaf(aa.w, wv8[3], acc4[r]);
        acc4[r] = fmaf(ab.x, wv8[4], acc4[r]);
        acc4[r] = fmaf(ab.y, wv8[5], acc4[r]);
        acc4[r] = fmaf(ab.z, wv8[6], acc4[r]);
        acc4[r] = fmaf(ab.w, wv8[7], acc4[r]);
      }
    }
#pragma unroll
    for (int r = 0; r < 4; ++r) a.sP[jh][r * 128 + c] = acc4[r];
  }
  __syncthreads();
  {
    int r = t >> 7, c = t & 127;
    a.soc[r][c] = a.sP[0][r * 128 + c] + a.sP[1][r * 128 + c] +
                  a.sP[2][r * 128 + c] + a.sP[3][r * 128 + c];
  }
  __syncthreads();
  // phase D: X1 = soc @ Wo + bo; k-split 8 x row-half 2
  {
    const int cg  = (t & 31) * 4;
    const int seg = (t >> 5) & 7;
    const int rh  = t >> 8;
    const int k0  = seg * 16;
    float acc[2][4] = {};
    float av[2][8];
#pragma unroll
    for (int kb = 0; kb < 16; kb += 8) {
      LD_AV2(a.soc[rh * 2], a.soc[rh * 2 + 1], k0 + kb, av);
      GB8_R2(p.Wo + cg, 128, k0 + kb, av, acc);
    }
#pragma unroll
    for (int r = 0; r < 2; ++r)
      *(float4*)&a.sP[seg][(rh * 2 + r) * 128 + cg] = *(float4*)acc[r];
  }
  __syncthreads();
  {
    int r = t >> 7, col = t & 127;
    float x = p.bo[col];
#pragma unroll
    for (int sg = 0; sg < 8; ++sg) x += a.sP[sg][r * 128 + col];
    ws[WS_X1 + (size_t)(row0 + r) * 128 + col] = x;
    a.sS[t] = x; a.sQ[t] = x * x;
  }
  __syncthreads();
  if (t < 128) {
    ws[BN1P + blk * 256 + t] =
        a.sS[t] + a.sS[t+128] + a.sS[t+256] + a.sS[t+384];
    ws[BN1P + blk * 256 + 128 + t] =
        a.sQ[t] + a.sQ[t+128] + a.sQ[t+256] + a.sQ[t+384];
  }
}

// ---- red phases -----------------------------------------------------------
__device__ __forceinline__ void red_cols(const P& p, int blk, SmR& r,
                                         int src, int dst) {
  const int t = threadIdx.x;
  const int col = blk * 8 + (t & 7);
  const int strip = t >> 3;            // 0..63
  float s = 0.f;
  for (int j = strip; j < 500; j += 64) s += p.ws[src + j * 256 + col];
  r.stage[t] = s;
  __syncthreads();
  if (t < 8) {
    float x = 0.f;
#pragma unroll
    for (int k = 0; k < 64; ++k) x += r.stage[k * 8 + t];
    p.ws[dst + blk * 8 + t] = x;
  }
}

__device__ __forceinline__ void uc0_phase(const P& p, SmR& r) {
  const int t = threadIdx.x;
  const int c = t & 127, g = t >> 7;
  float u = 0.f, cc = 0.f;
#pragma unroll 8
  for (int e = g * 32; e < g * 32 + 32; ++e) {
    float wn = p.Wn[(size_t)(128 + e) * 128 + c];
    u  = fmaf(p.Wd[e], wn, u);
    cc = fmaf(p.bd[e], wn, cc);
  }
  r.stage[t] = u;
  __syncthreads();
  if (t < 128)
    p.ws[WS_UV + t] = r.stage[t] + r.stage[t+128] + r.stage[t+256] + r.stage[t+384];
  __syncthreads();
  r.stage[t] = cc;
  __syncthreads();
  if (t < 128)
    p.ws[WS_C0V + t] = r.stage[t] + r.stage[t+128] + r.stage[t+256] +
                       r.stage[t+384] + p.bnn[t];
}

// ---- ffn phase: BN1 -> FFN -> X2 + BN2 partials ---------------------------
__device__ __forceinline__ void ffn_phase(const P& p, int blk, SmF& f) {
  const int t = threadIdx.x;
  const int row0 = blk * 4;
  float* ws = p.ws;
  const int c0 = t & 127;
  float m1 = ws[WS_SUM1 + c0] * 5e-4f;
  float v1 = ws[WS_SQ1 + c0] * 5e-4f - m1 * m1;
  float scv = p.g1[c0] * rsqrtf(v1 + BN_EPS);
  float shv = p.bb1[c0] - m1 * scv;
  {
    int r = t >> 7;
    f.o1[r][c0] = ws[WS_X1 + (size_t)(row0 + r) * 128 + c0] * scv + shv;
  }
  __syncthreads();
  // GEMM1 (128->512): cg(128 x 4cols) x kseg(4 x 32k)
  {
    const int cg   = (t & 127) * 4;
    const int kseg = t >> 7;
    const int kb0  = kseg * 32;
    float acc[4][4] = {};
#pragma unroll
    for (int kb = 0; kb < 32; kb += 4)
      GB4_R4(p.W1 + cg, 512, kb0 + kb, f.o1, acc);
#pragma unroll
    for (int r = 0; r < 4; ++r)
      *(float4*)&f.sP[kseg][r][cg] = *(float4*)acc[r];
  }
  __syncthreads();
#pragma unroll
  for (int i = 0; i < 4; ++i) {
    int idx = t + i * 512;
    int r = idx >> 9, c = idx & 511;
    float x = f.sP[0][r][c] + f.sP[1][r][c] + f.sP[2][r][c] + f.sP[3][r][c];
    f.sY[r][c] = fmaxf(x + p.b1[c], 0.f);
  }
  __syncthreads();
  // GEMM2 (512->128): cg(32 x 4cols) x kseg(16 x 32k)
  float* p2 = &f.sP[0][0][0];          // [16][4][128] view
  {
    const int cg   = (t & 31) * 4;
    const int kseg = t >> 5;
    const int kb0  = kseg * 32;
    float acc[4][4] = {};
#pragma unroll
    for (int kb = 0; kb < 32; kb += 4)
      GB4_R4(p.W2 + cg, 128, kb0 + kb, f.sY, acc);
#pragma unroll
    for (int r = 0; r < 4; ++r)
      *(float4*)(p2 + (size_t)(kseg * 4 + r) * 128 + cg) = *(float4*)acc[r];
  }
  __syncthreads();
  {
    int r = t >> 7, c = t & 127;
    float x = p.b2[c] + f.o1[r][c];
#pragma unroll
    for (int sg = 0; sg < 16; ++sg) x += p2[(size_t)(sg * 4 + r) * 128 + c];
    ws[WS_X2 + (size_t)(row0 + r) * 128 + c] = x;
    f.sS[t] = x; f.sQ[t] = x * x;
  }
  __syncthreads();
  if (t < 128) {
    ws[BN2P + blk * 256 + t] =
        f.sS[t] + f.sS[t+128] + f.sS[t+256] + f.sS[t+384];
    ws[BN2P + blk * 256 + 128 + t] =
        f.sQ[t] + f.sQ[t+128] + f.sQ[t+256] + f.sQ[t+384];
  }
}

// ---- final phase: BN2 -> out3 @ Wn_top + demand*U + C0 -> out -------------
__device__ __forceinline__ void final_phase(const P& p, int blk, SmC& c) {
  const int t = threadIdx.x;
  const int row0 = blk * 4;
  float* ws = p.ws;
  const int c0 = t & 127;
  float m2 = ws[WS_SUM2 + c0] * 5e-4f;
  float v2 = ws[WS_SQ2 + c0] * 5e-4f - m2 * m2;
  float scv = p.g2[c0] * rsqrtf(v2 + BN_EPS);
  float shv = p.bb2[c0] - m2 * scv;
  {
    int r = t >> 7;
    c.o3[r][c0] = ws[WS_X2 + (size_t)(row0 + r) * 128 + c0] * scv + shv;
  }
  __syncthreads();
  {
    const int cg  = (t & 31) * 4;
    const int seg = (t >> 5) & 7;
    const int rh  = t >> 8;
    const int k0  = seg * 16;
    float acc[2][4] = {};
    float av[2][8];
#pragma unroll
    for (int kb = 0; kb < 16; kb += 8) {
      LD_AV2(c.o3[rh * 2], c.o3[rh * 2 + 1], k0 + kb, av);
      GB8_R2(p.Wn + cg, 128, k0 + kb, av, acc);
    }
#pragma unroll
    for (int r = 0; r < 2; ++r)
      *(float4*)&c.sP[seg][rh * 2 + r][cg] = *(float4*)acc[r];
  }
  __syncthreads();
  {
    int r = t >> 7;
    float x = ws[WS_C0V + c0] + p.dem[row0 + r] * ws[WS_UV + c0];
#pragma unroll
    for (int sg = 0; sg < 8; ++sg) x += c.sP[sg][r][c0];
    p.out[(size_t)(row0 + r) * 128 + c0] = x;
  }
}

// ---- mega kernel (cooperative, 250 blocks x 512) --------------------------
__global__ __launch_bounds__(512, 2) void k_mega(P p) {
  cg::grid_group grid = cg::this_grid();
  __shared__ Sm sm;
  const int bid = blockIdx.x;
  attn_phase(p, bid, sm.a);
  __syncthreads();
  attn_phase(p, bid + 250, sm.a);
  grid.sync();
  if (bid < 32) red_cols(p, bid, sm.r, BN1P, WS_SUM1);
  else if (bid == 32) uc0_phase(p, sm.r);
  grid.sync();
  ffn_phase(p, bid, sm.f);
  __syncthreads();
  ffn_phase(p, bid + 250, sm.f);
  grid.sync();
  if (bid < 32) red_cols(p, bid, sm.r, BN2P, WS_SUM2);
  grid.sync();
  final_phase(p, bid, sm.c);
  __syncthreads();
  final_phase(p, bid + 250, sm.c);
}

// ---- fallback standalone kernels (R14-equivalent chain) -------------------
__global__ __launch_bounds__(512, 4) void k_attn_s(P p) {
  __shared__ SmA a;
  attn_phase(p, blockIdx.x, a);
}
__global__ __launch_bounds__(512) void k_red1_s(P p) {
  __shared__ SmR r;
  if (blockIdx.x < 32) red_cols(p, blockIdx.x, r, BN1P, WS_SUM1);
  else uc0_phase(p, r);
}
__global__ __launch_bounds__(512, 2) void k_ffn_s(P p) {
  __shared__ SmF f;
  ffn_phase(p, blockIdx.x, f);
}
__global__ __launch_bounds__(512) void k_red2_s(P p) {
  __shared__ SmR r;
  red_cols(p, blockIdx.x, r, BN2P, WS_SUM2);
}
__global__ __launch_bounds__(512, 4) void k_final_s(P p) {
  __shared__ SmC c;
  final_phase(p, blockIdx.x, c);
}

extern "C" void kernel_launch(void* const* d_in, const int* in_sizes, int n_in,
                              void* d_out, int out_size, void* d_ws, size_t ws_size,
                              hipStream_t stream) {
  P p;
  p.cost  = (const float*)d_in[0];
  p.dem   = (const float*)d_in[1];
  p.rnd   = (const float*)d_in[2];
  // d_in[3] Wq, d_in[4] Wk unused (q == 0)
  p.Wv    = (const float*)d_in[5];
  p.mix1w = (const float*)d_in[6];
  p.mix1b = (const float*)d_in[7];
  p.mix2w = (const float*)d_in[8];
  p.mix2b = (const float*)d_in[9];
  p.Wo    = (const float*)d_in[10];
  p.bo    = (const float*)d_in[11];
  p.W1    = (const float*)d_in[12];
  p.b1    = (const float*)d_in[13];
  p.W2    = (const float*)d_in[14];
  p.b2    = (const float*)d_in[15];
  p.g1    = (const float*)d_in[16];
  p.bb1   = (const float*)d_in[17];
  p.g2    = (const float*)d_in[18];
  p.bb2   = (const float*)d_in[19];
  p.Wd    = (const float*)d_in[20];
  p.bd    = (const float*)d_in[21];
  p.Wn    = (const float*)d_in[22];
  p.bnn   = (const float*)d_in[23];
  p.out   = (float*)d_out;
  p.ws    = (float*)d_ws;

  void* args[] = { (void*)&p };
  hipError_t rc = hipLaunchCooperativeKernel((const void*)k_mega, dim3(250),
                                             dim3(512), args, 0, stream);
  if (rc != hipSuccess) {
    (void)hipGetLastError();   // clear sticky error; use validated 5-kernel chain
    hipLaunchKernelGGL(k_attn_s,  dim3(500), dim3(512), 0, stream, p);
    hipLaunchKernelGGL(k_red1_s,  dim3(33),  dim3(512), 0, stream, p);
    hipLaunchKernelGGL(k_ffn_s,   dim3(500), dim3(512), 0, stream, p);
    hipLaunchKernelGGL(k_red2_s,  dim3(32),  dim3(512), 0, stream, p);
    hipLaunchKernelGGL(k_final_s, dim3(500), dim3(512), 0, stream, p);
  }
}